// Round 10
// baseline (59.396 us; speedup 1.0000x reference)
//
#include <hip/hip_runtime.h>

// Problem constants
constexpr int cN1 = 85,  cF1 = 256, cO1 = 200, cE1 = 1360;
constexpr int cN2 = 5625, cF2 = 128, cE2 = 180000;

// deg2: NPART edge-sliced partial LDS histograms (plain-stored, no atomics)
constexpr int NPART = 8;
constexpr int PBINS = 5632;              // >= cN2, 64-aligned
constexpr int EPP   = cE2 / NPART;       // 22500

// g2 aggregation: NS edge-slices x NR node-ranges, partials in LDS, plain-stored.
constexpr int NS  = 16;                  // edge slices
constexpr int ESL = cE2 / NS;            // 11250 edges per slice
constexpr int NR  = 16;                  // node ranges
constexpr int RNG = PBINS / NR;          // 352 nodes per range

// Workspace layout (4-byte words) — nothing needs pre-zeroing:
constexpr int OFF_PART = 0;                          // 8*5632 i32 deg partials
constexpr int OFF_P2   = NPART * PBINS;              // 45056: NS*PBINS*2 f32 g2 partials
constexpr int OFF_DINV = OFF_P2 + NS * PBINS * 2;    // 225280: 5632 f32 dinv2 table
constexpr int OFF_HS2  = OFF_DINV + PBINS;           // 230912: 5632*2 f32 dinv*h2 (even)
constexpr int OFF_G1   = OFF_HS2 + PBINS * 2;        // 242176: 17000 f32
constexpr int OFF_H1   = OFF_G1 + cN1 * cO1;         // 259176: 17000 f32 (x1@W1)
constexpr int OFF_H2   = OFF_H1 + cN1 * cO1;         // 276176: 11250 f32 (x2@W2), even

// ---------------- K1: deg partial hists + GEMMs (role-split grid) ---------------
// roles: [0,8) hist | [8,93) GEMM1 | [93,797) GEMM2
constexpr int G1_B    = cN1;                  // 85
constexpr int G2_B    = (cN2 + 7) / 8;        // 704
constexpr int K1_GRID = NPART + G1_B + G2_B;  // 797

__global__ __launch_bounds__(256) void k1_hist_gemm(
    const float* __restrict__ x1, const float* __restrict__ x2,
    const float* __restrict__ W1, const float* __restrict__ W2,
    const int* __restrict__ ei2, float* __restrict__ ws_f)
{
    int* ws_i = reinterpret_cast<int*>(ws_f);
    int b = blockIdx.x, t = threadIdx.x;

    if (b < NPART) {
        // Partial histogram over edge slice [b*EPP, (b+1)*EPP)
        __shared__ int s_h[PBINS];
        for (int i = t; i < PBINS; i += 256) s_h[i] = 0;
        __syncthreads();
        const int* dstp = ei2 + cE2 + b * EPP;
        for (int i = t; i < EPP; i += 256)
            atomicAdd(&s_h[dstp[i]], 1);              // LDS atomic only
        __syncthreads();
        for (int i = t; i < PBINS; i += 256)
            ws_i[OFF_PART + b * PBINS + i] = s_h[i];  // plain store
        return;
    }
    b -= NPART;

    if (b < G1_B) {
        // GEMM1: h1[b][t] = sum_k x1[b][k] * W1[k][t]  (t < 200)
        if (t < cO1) {
            const float* xr = x1 + b * cF1;           // uniform across block
            float s = 0.f;
            #pragma unroll 8
            for (int k = 0; k < cF1; ++k)
                s = fmaf(xr[k], W1[k * cO1 + t], s);  // coalesced across t
            ws_f[OFF_H1 + b * cO1 + t] = s;
        }
        return;
    }
    b -= G1_B;

    // GEMM2: 32-lane group per row; W2 (1 KB) cache-resident.
    int row = b * 8 + (t >> 5), l = t & 31;
    if (row < cN2) {
        float4 xv = reinterpret_cast<const float4*>(x2 + row * cF2)[l];
        int kb = l * 4;
        float p0 = xv.x * W2[(kb + 0) * 2 + 0] + xv.y * W2[(kb + 1) * 2 + 0]
                 + xv.z * W2[(kb + 2) * 2 + 0] + xv.w * W2[(kb + 3) * 2 + 0];
        float p1 = xv.x * W2[(kb + 0) * 2 + 1] + xv.y * W2[(kb + 1) * 2 + 1]
                 + xv.z * W2[(kb + 2) * 2 + 1] + xv.w * W2[(kb + 3) * 2 + 1];
        #pragma unroll
        for (int m = 16; m >= 1; m >>= 1) {
            p0 += __shfl_xor(p0, m);
            p1 += __shfl_xor(p1, m);
        }
        if (l == 0) {
            ws_f[OFF_H2 + row * 2 + 0] = p0;
            ws_f[OFF_H2 + row * 2 + 1] = p1;
        }
    }
}

// ---------------- K2: dinv2 + hs2 tables (pointwise; all loads coalesced) -------
constexpr int K2_GRID = PBINS / 256;     // 22

__global__ __launch_bounds__(256) void k2_table(float* __restrict__ ws_f)
{
    const int* ws_i = reinterpret_cast<const int*>(ws_f);
    int n = blockIdx.x * 256 + threadIdx.x;
    if (n >= cN2) return;
    int d = 0;
    #pragma unroll
    for (int p = 0; p < NPART; ++p) d += ws_i[OFF_PART + p * PBINS + n];  // coalesced
    float dv = rsqrtf((float)(d + 1));
    ws_f[OFF_DINV + n] = dv;
    float2 h = reinterpret_cast<const float2*>(ws_f + OFF_H2)[n];
    reinterpret_cast<float2*>(ws_f + OFF_HS2)[n] = make_float2(dv * h.x, dv * h.y);
}

// ---------------- K3: g1 gather + g2 sliced gather (plain stores only) ----------
// roles: [0,85) g1 | [85, 85+NS*NR) g2 partial gather
constexpr int K3_GRID = cN1 + NS * NR;   // 341

__global__ __launch_bounds__(256) void k3_gather(
    const int* __restrict__ ei1, const int* __restrict__ ei2,
    float* __restrict__ ws_f)
{
    int b = blockIdx.x, t = threadIdx.x;

    if (b < cN1) {
        // graph1: self-contained gather (deg1 in LDS; no global atomics)
        __shared__ int   s_src[cE1];
        __shared__ int   s_dst[cE1];
        __shared__ int   s_deg[cN1];
        __shared__ float s_acc[cO1];
        for (int i = t; i < cE1; i += 256) { s_src[i] = ei1[i]; s_dst[i] = ei1[cE1 + i]; }
        if (t < cN1) s_deg[t] = 0;
        for (int i = t; i < cO1; i += 256) s_acc[i] = 0.f;
        __syncthreads();
        for (int i = t; i < cE1; i += 256) atomicAdd(&s_deg[s_dst[i]], 1);
        __syncthreads();
        int w = t >> 6, lane = t & 63;
        int e0 = w * (cE1 / 4), e1 = e0 + (cE1 / 4);       // 340 edges / wave
        for (int e = e0; e < e1; ++e) {
            if (s_dst[e] == b) {
                int src = s_src[e];
                float dsv = rsqrtf((float)(s_deg[src] + 1));
                const float* hrow = ws_f + OFF_H1 + src * cO1;
                for (int f = lane; f < cO1; f += 64)
                    atomicAdd(&s_acc[f], hrow[f] * dsv);   // LDS atomic, sparse
            }
        }
        __syncthreads();
        float dn = rsqrtf((float)(s_deg[b] + 1));
        for (int i = t; i < cO1; i += 256)
            ws_f[OFF_G1 + b * cO1 + i] =
                dn * (s_acc[i] + dn * ws_f[OFF_H1 + b * cO1 + i]);
        return;
    }
    b -= cN1;

    // graph2 partial gather: slice s of edges, node range [lo, lo+RNG)
    int s = b >> 4, r = b & 15;
    int lo = r * RNG;
    __shared__ float s_acc2[RNG * 2];                  // 2816 B
    for (int i = t; i < RNG * 2; i += 256) s_acc2[i] = 0.f;
    __syncthreads();
    int e0 = s * ESL;
    for (int i = t; i < ESL; i += 256) {
        int e = e0 + i;
        int d = ei2[cE2 + e];                          // coalesced
        unsigned rel = (unsigned)(d - lo);
        if (rel < (unsigned)RNG) {
            int src = ei2[e];
            float2 hv = reinterpret_cast<const float2*>(ws_f + OFF_HS2)[src];
            atomicAdd(&s_acc2[rel * 2 + 0], hv.x);     // LDS atomic
            atomicAdd(&s_acc2[rel * 2 + 1], hv.y);
        }
    }
    __syncthreads();
    // plain-store partials: part2[s][lo+j][c]
    float* dst = ws_f + OFF_P2 + (s * PBINS + lo) * 2;
    for (int i = t; i < RNG * 2; i += 256) dst[i] = s_acc2[i];
}

// ---------------- K4: reduce partials + bias + concat + relu + final linear -----
__global__ __launch_bounds__(128) void k4_head(
    const float* __restrict__ ws_f,
    const float* __restrict__ b1, const float* __restrict__ b2,
    const float* __restrict__ Wf, const float* __restrict__ bf,
    float* __restrict__ out)
{
    __shared__ float sh[113];
    int r = blockIdx.x, t = threadIdx.x;
    if (t < 113) {
        float v;
        if (t < 68) {
            int f = r * 68 + t;                       // h1.reshape(250,68) flat
            v = ws_f[OFF_G1 + f] + b1[f % 200];
        } else {
            int f = r * 45 + (t - 68);                // h2.reshape(250,45) flat
            int n = f >> 1, c = f & 1;
            float sum = ws_f[OFF_HS2 + n * 2 + c];    // self loop: dinv*h2
            #pragma unroll
            for (int s = 0; s < NS; ++s)
                sum += ws_f[OFF_P2 + (s * PBINS + n) * 2 + c];
            v = ws_f[OFF_DINV + n] * sum + b2[c];
        }
        sh[t] = fmaxf(v, 0.f);
    }
    __syncthreads();
    if (t < 5) {
        float s = bf[t];
        #pragma unroll 1
        for (int k = 0; k < 113; ++k)
            s = fmaf(sh[k], Wf[k * 5 + t], s);
        out[r * 5 + t] = s;
    }
}

extern "C" void kernel_launch(void* const* d_in, const int* in_sizes, int n_in,
                              void* d_out, int out_size, void* d_ws, size_t ws_size,
                              hipStream_t stream)
{
    const float* x1 = (const float*)d_in[0];
    const float* x2 = (const float*)d_in[1];
    const float* W1 = (const float*)d_in[2];
    const float* b1 = (const float*)d_in[3];
    const float* W2 = (const float*)d_in[4];
    const float* b2 = (const float*)d_in[5];
    const float* Wf = (const float*)d_in[6];
    const float* bf = (const float*)d_in[7];
    const int*   ei1 = (const int*)d_in[8];
    const int*   ei2 = (const int*)d_in[9];
    float* ws_f = (float*)d_ws;
    float* out  = (float*)d_out;

    k1_hist_gemm<<<K1_GRID, 256, 0, stream>>>(x1, x2, W1, W2, ei2, ws_f);
    k2_table<<<K2_GRID, 256, 0, stream>>>(ws_f);
    k3_gather<<<K3_GRID, 256, 0, stream>>>(ei1, ei2, ws_f);
    k4_head<<<250, 128, 0, stream>>>(ws_f, b1, b2, Wf, bf, out);
}

// Round 11
// 41.909 us; speedup vs baseline: 1.4173x; 1.4173x over previous
//
#include <hip/hip_runtime.h>

// Problem constants
constexpr int cN1 = 85,  cF1 = 256, cO1 = 200, cE1 = 1360;
constexpr int cN2 = 5625, cF2 = 128, cE2 = 180000;

// deg2: NPART edge-sliced partial LDS histograms (plain-stored, no atomics)
constexpr int NPART = 8;
constexpr int PBINS = 5632;              // >= cN2, 64-aligned
constexpr int EPP   = cE2 / NPART;       // 22500

// g2 aggregation: NS edge slices; each block builds a FULL-range [PBINS][2]
// partial in LDS (no node-range predicate -> branch-free, pipelineable scan).
constexpr int NS  = 90;
constexpr int ESL = cE2 / NS;            // 2000 edges per slice

// Workspace layout (4-byte words) — nothing needs pre-zeroing:
constexpr int OFF_PART  = 0;                         // 8*5632 i32 deg partials
constexpr int OFF_P2    = NPART * PBINS;             // 45056: NS*PBINS*2 f32
constexpr int OFF_DINV  = OFF_P2 + NS * PBINS * 2;   // 1058816: 5632 f32
constexpr int OFF_HS2   = OFF_DINV + PBINS;          // 1064448: 5632*2 f32 (even)
constexpr int OFF_DINV1 = OFF_HS2 + PBINS * 2;       // 1075712: 85 f32 (+pad)
constexpr int OFF_G1    = OFF_DINV1 + 128;           // 1075840: 17000 f32
constexpr int OFF_H1    = OFF_G1 + cN1 * cO1;        // 1092840: 17000 f32 (x1@W1)
constexpr int OFF_H2    = OFF_H1 + cN1 * cO1;        // 1109840: 11250 f32 (even)

// ---------------- K1: deg partial hists + GEMMs (role-split grid) ---------------
constexpr int G1_B    = cN1;                  // 85
constexpr int G2_B    = (cN2 + 7) / 8;        // 704
constexpr int K1_GRID = NPART + G1_B + G2_B;  // 797

__global__ __launch_bounds__(256) void k1_hist_gemm(
    const float* __restrict__ x1, const float* __restrict__ x2,
    const float* __restrict__ W1, const float* __restrict__ W2,
    const int* __restrict__ ei2, float* __restrict__ ws_f)
{
    int* ws_i = reinterpret_cast<int*>(ws_f);
    int b = blockIdx.x, t = threadIdx.x;

    if (b < NPART) {
        __shared__ int s_h[PBINS];
        for (int i = t; i < PBINS; i += 256) s_h[i] = 0;
        __syncthreads();
        const int* dstp = ei2 + cE2 + b * EPP;
        for (int i = t; i < EPP; i += 256)
            atomicAdd(&s_h[dstp[i]], 1);              // LDS atomic only
        __syncthreads();
        for (int i = t; i < PBINS; i += 256)
            ws_i[OFF_PART + b * PBINS + i] = s_h[i];  // plain store
        return;
    }
    b -= NPART;

    if (b < G1_B) {
        // GEMM1: h1[b][t] = sum_k x1[b][k] * W1[k][t]  (t < 200)
        if (t < cO1) {
            const float* xr = x1 + b * cF1;           // uniform across block
            float s = 0.f;
            #pragma unroll 8
            for (int k = 0; k < cF1; ++k)
                s = fmaf(xr[k], W1[k * cO1 + t], s);  // coalesced across t
            ws_f[OFF_H1 + b * cO1 + t] = s;
        }
        return;
    }
    b -= G1_B;

    // GEMM2: 32-lane group per row; W2 (1 KB) cache-resident.
    int row = b * 8 + (t >> 5), l = t & 31;
    if (row < cN2) {
        float4 xv = reinterpret_cast<const float4*>(x2 + row * cF2)[l];
        int kb = l * 4;
        float p0 = xv.x * W2[(kb + 0) * 2 + 0] + xv.y * W2[(kb + 1) * 2 + 0]
                 + xv.z * W2[(kb + 2) * 2 + 0] + xv.w * W2[(kb + 3) * 2 + 0];
        float p1 = xv.x * W2[(kb + 0) * 2 + 1] + xv.y * W2[(kb + 1) * 2 + 1]
                 + xv.z * W2[(kb + 2) * 2 + 1] + xv.w * W2[(kb + 3) * 2 + 1];
        #pragma unroll
        for (int m = 16; m >= 1; m >>= 1) {
            p0 += __shfl_xor(p0, m);
            p1 += __shfl_xor(p1, m);
        }
        if (l == 0) {
            ws_f[OFF_H2 + row * 2 + 0] = p0;
            ws_f[OFF_H2 + row * 2 + 1] = p1;
        }
    }
}

// ---------------- K2: dinv2 + hs2 tables + dinv1 table --------------------------
constexpr int K2_GRID = PBINS / 256 + 1;     // 22 + 1 (deg1/dinv1 block)

__global__ __launch_bounds__(256) void k2_table(
    const int* __restrict__ ei1, float* __restrict__ ws_f)
{
    const int* ws_i = reinterpret_cast<const int*>(ws_f);
    int b = blockIdx.x, t = threadIdx.x;

    if (b < PBINS / 256) {
        int n = b * 256 + t;
        if (n >= cN2) return;
        int d = 0;
        #pragma unroll
        for (int p = 0; p < NPART; ++p) d += ws_i[OFF_PART + p * PBINS + n];
        float dv = rsqrtf((float)(d + 1));
        ws_f[OFF_DINV + n] = dv;
        float2 h = reinterpret_cast<const float2*>(ws_f + OFF_H2)[n];
        reinterpret_cast<float2*>(ws_f + OFF_HS2)[n] = make_float2(dv * h.x, dv * h.y);
        return;
    }
    // deg1 histogram -> dinv1 table (85 nodes)
    __shared__ int s_deg[cN1];
    if (t < cN1) s_deg[t] = 0;
    __syncthreads();
    for (int i = t; i < cE1; i += 256) atomicAdd(&s_deg[ei1[cE1 + i]], 1);
    __syncthreads();
    if (t < cN1) ws_f[OFF_DINV1 + t] = rsqrtf((float)(s_deg[t] + 1));
}

// ---------------- K3: g1 match-list gather + g2 full-range sliced gather --------
// roles: [0,85) g1 node blocks | [85, 85+NS) g2 slice blocks
constexpr int K3_GRID = cN1 + NS;   // 175

__global__ __launch_bounds__(256) void k3_gather(
    const int* __restrict__ ei1, const int* __restrict__ ei2,
    float* __restrict__ ws_f)
{
    __shared__ float sm[2 * PBINS];          // 45 KB, shared by both roles
    int b = blockIdx.x, t = threadIdx.x;

    if (b < cN1) {
        // graph1 node b: parallel match scan -> LDS list -> register accumulate
        int* s_list = reinterpret_cast<int*>(sm);     // [0]=count, [1..]=srcs
        if (t == 0) s_list[0] = 0;
        __syncthreads();
        for (int i = t; i < cE1; i += 256) {          // 6 coalesced iterations
            int d = ei1[cE1 + i];
            if (d == b) {
                int k = atomicAdd(&s_list[0], 1) + 1;
                s_list[k] = ei1[i];
            }
        }
        __syncthreads();
        int cnt = s_list[0];
        if (t < cO1) {
            float acc = 0.f;
            for (int m = 1; m <= cnt; ++m) {          // ~16 iters, indep loads
                int s = s_list[m];
                acc = fmaf(ws_f[OFF_DINV1 + s], ws_f[OFF_H1 + s * cO1 + t], acc);
            }
            float dn = ws_f[OFF_DINV1 + b];
            ws_f[OFF_G1 + b * cO1 + t] =
                dn * (acc + dn * ws_f[OFF_H1 + b * cO1 + t]);
        }
        return;
    }
    int s = b - cN1;

    // graph2 slice s: branch-free full-range partial in LDS
    for (int i = t; i < 2 * PBINS; i += 256) sm[i] = 0.f;
    __syncthreads();
    const int e0 = s * ESL;
    #pragma unroll
    for (int batch = 0; batch < 2; ++batch) {
        int off = batch * 1024 + t * 4;
        if (off < ESL) {                              // whole int4 valid (ESL%4==0)
            int4 s4 = *reinterpret_cast<const int4*>(ei2 + e0 + off);
            int4 d4 = *reinterpret_cast<const int4*>(ei2 + cE2 + e0 + off);
            const float2* hs2 = reinterpret_cast<const float2*>(ws_f + OFF_HS2);
            float2 h0 = hs2[s4.x], h1 = hs2[s4.y], h2 = hs2[s4.z], h3 = hs2[s4.w];
            atomicAdd(&sm[d4.x * 2 + 0], h0.x); atomicAdd(&sm[d4.x * 2 + 1], h0.y);
            atomicAdd(&sm[d4.y * 2 + 0], h1.x); atomicAdd(&sm[d4.y * 2 + 1], h1.y);
            atomicAdd(&sm[d4.z * 2 + 0], h2.x); atomicAdd(&sm[d4.z * 2 + 1], h2.y);
            atomicAdd(&sm[d4.w * 2 + 0], h3.x); atomicAdd(&sm[d4.w * 2 + 1], h3.y);
        }
    }
    __syncthreads();
    float* dst = ws_f + OFF_P2 + s * PBINS * 2;
    for (int i = t; i < 2 * PBINS; i += 256) dst[i] = sm[i];   // coalesced stores
}

// ---------------- K4: reduce partials + bias + concat + relu + final linear -----
__global__ __launch_bounds__(128) void k4_head(
    const float* __restrict__ ws_f,
    const float* __restrict__ b1, const float* __restrict__ b2,
    const float* __restrict__ Wf, const float* __restrict__ bf,
    float* __restrict__ out)
{
    __shared__ float sh[113];
    int r = blockIdx.x, t = threadIdx.x;
    if (t < 113) {
        float v;
        if (t < 68) {
            int f = r * 68 + t;                       // h1.reshape(250,68) flat
            v = ws_f[OFF_G1 + f] + b1[f % 200];
        } else {
            int f = r * 45 + (t - 68);                // h2.reshape(250,45) flat
            int n = f >> 1, c = f & 1;
            float sum = ws_f[OFF_HS2 + n * 2 + c];    // self loop: dinv*h2
            #pragma unroll 10
            for (int p = 0; p < NS; ++p)
                sum += ws_f[OFF_P2 + p * PBINS * 2 + n * 2 + c];
            v = ws_f[OFF_DINV + n] * sum + b2[c];
        }
        sh[t] = fmaxf(v, 0.f);
    }
    __syncthreads();
    if (t < 5) {
        float s = bf[t];
        #pragma unroll 1
        for (int k = 0; k < 113; ++k)
            s = fmaf(sh[k], Wf[k * 5 + t], s);
        out[r * 5 + t] = s;
    }
}

extern "C" void kernel_launch(void* const* d_in, const int* in_sizes, int n_in,
                              void* d_out, int out_size, void* d_ws, size_t ws_size,
                              hipStream_t stream)
{
    const float* x1 = (const float*)d_in[0];
    const float* x2 = (const float*)d_in[1];
    const float* W1 = (const float*)d_in[2];
    const float* b1 = (const float*)d_in[3];
    const float* W2 = (const float*)d_in[4];
    const float* b2 = (const float*)d_in[5];
    const float* Wf = (const float*)d_in[6];
    const float* bf = (const float*)d_in[7];
    const int*   ei1 = (const int*)d_in[8];
    const int*   ei2 = (const int*)d_in[9];
    float* ws_f = (float*)d_ws;
    float* out  = (float*)d_out;

    k1_hist_gemm<<<K1_GRID, 256, 0, stream>>>(x1, x2, W1, W2, ei2, ws_f);
    k2_table<<<K2_GRID, 256, 0, stream>>>(ei1, ws_f);
    k3_gather<<<K3_GRID, 256, 0, stream>>>(ei1, ei2, ws_f);
    k4_head<<<250, 128, 0, stream>>>(ws_f, b1, b2, Wf, bf, out);
}

// Round 12
// 34.414 us; speedup vs baseline: 1.7260x; 1.2178x over previous
//
#include <hip/hip_runtime.h>

// Problem constants
constexpr int cN1 = 85,  cF1 = 256, cO1 = 200, cE1 = 1360;
constexpr int cN2 = 5625, cF2 = 128, cE2 = 180000;

// deg2: NPART edge-sliced partial LDS histograms (plain-stored, no atomics)
constexpr int NPART = 8;
constexpr int PBINS = 5632;              // >= cN2, 64-aligned
constexpr int EPP   = cE2 / NPART;       // 22500

// g2 aggregation: NS edge slices; each block builds a FULL-range [PBINS][2]
// partial in LDS (branch-free, pipelineable scan), plain-stored.
constexpr int NS  = 90;
constexpr int ESL = cE2 / NS;            // 2000 edges per slice

// Workspace layout (4-byte words) — nothing needs pre-zeroing:
constexpr int OFF_PART  = 0;                         // 8*5632 i32 deg partials
constexpr int OFF_P2    = NPART * PBINS;             // 45056: NS*PBINS*2 f32
constexpr int OFF_DINV  = OFF_P2 + NS * PBINS * 2;   // 1058816: 5632 f32
constexpr int OFF_HS2   = OFF_DINV + PBINS;          // 1064448: 5632*2 f32 (dinv*h2)
constexpr int OFF_DINV1 = OFF_HS2 + PBINS * 2;       // 1075712: 85 f32 (+pad)
constexpr int OFF_G1    = OFF_DINV1 + 128;           // 1075840: 17000 f32
constexpr int OFF_H1    = OFF_G1 + cN1 * cO1;        // 1092840: 17000 f32 (x1@W1)
// end = OFF_H1 + 17000 = 1109840 words ~= 4.44 MB

// ---------------- kA: deg2 partial hists + dinv1 + GEMM1 (role-split) -----------
constexpr int KA_GRID = NPART + 1 + cN1;   // 94

__global__ __launch_bounds__(256) void kA_hist_gemm1(
    const float* __restrict__ x1, const float* __restrict__ W1,
    const int* __restrict__ ei1, const int* __restrict__ ei2,
    float* __restrict__ ws_f)
{
    int* ws_i = reinterpret_cast<int*>(ws_f);
    int b = blockIdx.x, t = threadIdx.x;

    if (b < NPART) {
        // Partial histogram over edge slice [b*EPP, (b+1)*EPP)
        __shared__ int s_h[PBINS];
        for (int i = t; i < PBINS; i += 256) s_h[i] = 0;
        __syncthreads();
        const int* dstp = ei2 + cE2 + b * EPP;
        #pragma unroll 4
        for (int i = t; i < EPP; i += 256)
            atomicAdd(&s_h[dstp[i]], 1);              // LDS atomic only
        __syncthreads();
        for (int i = t; i < PBINS; i += 256)
            ws_i[OFF_PART + b * PBINS + i] = s_h[i];  // plain store
        return;
    }
    b -= NPART;

    if (b == 0) {
        // deg1 histogram -> dinv1 table (85 nodes)
        __shared__ int s_deg[cN1];
        if (t < cN1) s_deg[t] = 0;
        __syncthreads();
        for (int i = t; i < cE1; i += 256) atomicAdd(&s_deg[ei1[cE1 + i]], 1);
        __syncthreads();
        if (t < cN1) ws_f[OFF_DINV1 + t] = rsqrtf((float)(s_deg[t] + 1));
        return;
    }
    b -= 1;

    // GEMM1: h1[b][t] = sum_k x1[b][k] * W1[k][t]  (t < 200)
    if (t < cO1) {
        const float* xr = x1 + b * cF1;               // uniform across block
        float s = 0.f;
        #pragma unroll 16
        for (int k = 0; k < cF1; ++k)
            s = fmaf(xr[k], W1[k * cO1 + t], s);      // coalesced across t
        ws_f[OFF_H1 + b * cO1 + t] = s;
    }
}

// ---------------- kB: GEMM2 fused with dinv2/hs2 table production ---------------
constexpr int KB_GRID = (cN2 + 7) / 8;     // 704

__global__ __launch_bounds__(256) void kB_gemm2_table(
    const float* __restrict__ x2, const float* __restrict__ W2,
    float* __restrict__ ws_f)
{
    const int* ws_i = reinterpret_cast<const int*>(ws_f);
    int b = blockIdx.x, t = threadIdx.x;
    int row = b * 8 + (t >> 5), l = t & 31;
    if (row >= cN2) return;

    float4 xv = reinterpret_cast<const float4*>(x2 + row * cF2)[l];
    int kb = l * 4;
    float p0 = xv.x * W2[(kb + 0) * 2 + 0] + xv.y * W2[(kb + 1) * 2 + 0]
             + xv.z * W2[(kb + 2) * 2 + 0] + xv.w * W2[(kb + 3) * 2 + 0];
    float p1 = xv.x * W2[(kb + 0) * 2 + 1] + xv.y * W2[(kb + 1) * 2 + 1]
             + xv.z * W2[(kb + 2) * 2 + 1] + xv.w * W2[(kb + 3) * 2 + 1];
    #pragma unroll
    for (int m = 16; m >= 1; m >>= 1) {
        p0 += __shfl_xor(p0, m);
        p1 += __shfl_xor(p1, m);
    }
    if (l == 0) {
        int d = 0;
        #pragma unroll
        for (int p = 0; p < NPART; ++p) d += ws_i[OFF_PART + p * PBINS + row];
        float dv = rsqrtf((float)(d + 1));
        ws_f[OFF_DINV + row] = dv;
        reinterpret_cast<float2*>(ws_f + OFF_HS2)[row] =
            make_float2(dv * p0, dv * p1);            // hs2 = dinv * h2
    }
}

// ---------------- kC: g1 match-list gather + g2 full-range sliced gather --------
// roles: [0,85) g1 node blocks | [85, 85+NS) g2 slice blocks
constexpr int KC_GRID = cN1 + NS;   // 175

__global__ __launch_bounds__(256) void kC_gather(
    const int* __restrict__ ei1, const int* __restrict__ ei2,
    float* __restrict__ ws_f)
{
    __shared__ float sm[2 * PBINS];          // 45 KB, shared by both roles
    int b = blockIdx.x, t = threadIdx.x;

    if (b < cN1) {
        // graph1 node b: parallel match scan -> LDS list -> register accumulate
        int* s_list = reinterpret_cast<int*>(sm);     // [0]=count, [1..]=srcs
        if (t == 0) s_list[0] = 0;
        __syncthreads();
        for (int i = t; i < cE1; i += 256) {          // 6 coalesced iterations
            int d = ei1[cE1 + i];
            if (d == b) {
                int k = atomicAdd(&s_list[0], 1) + 1;
                s_list[k] = ei1[i];
            }
        }
        __syncthreads();
        int cnt = s_list[0];
        if (t < cO1) {
            float acc = 0.f;
            for (int m = 1; m <= cnt; ++m) {          // ~16 iters, indep loads
                int s = s_list[m];
                acc = fmaf(ws_f[OFF_DINV1 + s], ws_f[OFF_H1 + s * cO1 + t], acc);
            }
            float dn = ws_f[OFF_DINV1 + b];
            ws_f[OFF_G1 + b * cO1 + t] =
                dn * (acc + dn * ws_f[OFF_H1 + b * cO1 + t]);
        }
        return;
    }
    int s = b - cN1;

    // graph2 slice s: branch-free full-range partial in LDS
    for (int i = t; i < 2 * PBINS; i += 256) sm[i] = 0.f;
    __syncthreads();
    const int e0 = s * ESL;
    #pragma unroll
    for (int batch = 0; batch < 2; ++batch) {
        int off = batch * 1024 + t * 4;
        if (off < ESL) {                              // whole int4 valid (ESL%4==0)
            int4 s4 = *reinterpret_cast<const int4*>(ei2 + e0 + off);
            int4 d4 = *reinterpret_cast<const int4*>(ei2 + cE2 + e0 + off);
            const float2* hs2 = reinterpret_cast<const float2*>(ws_f + OFF_HS2);
            float2 h0 = hs2[s4.x], h1 = hs2[s4.y], h2 = hs2[s4.z], h3 = hs2[s4.w];
            atomicAdd(&sm[d4.x * 2 + 0], h0.x); atomicAdd(&sm[d4.x * 2 + 1], h0.y);
            atomicAdd(&sm[d4.y * 2 + 0], h1.x); atomicAdd(&sm[d4.y * 2 + 1], h1.y);
            atomicAdd(&sm[d4.z * 2 + 0], h2.x); atomicAdd(&sm[d4.z * 2 + 1], h2.y);
            atomicAdd(&sm[d4.w * 2 + 0], h3.x); atomicAdd(&sm[d4.w * 2 + 1], h3.y);
        }
    }
    __syncthreads();
    float* dst = ws_f + OFF_P2 + s * PBINS * 2;
    for (int i = t; i < 2 * PBINS; i += 256) dst[i] = sm[i];   // coalesced stores
}

// ---------------- kD: parallel partial-reduce + bias + relu + final linear ------
__global__ __launch_bounds__(128) void kD_head(
    const float* __restrict__ ws_f,
    const float* __restrict__ b1, const float* __restrict__ b2,
    const float* __restrict__ Wf, const float* __restrict__ bf,
    float* __restrict__ out)
{
    __shared__ float sred[45][2];
    __shared__ float sh[113];
    int r = blockIdx.x, t = threadIdx.x;

    // Phase A: reduce the NS=90 g2 partials; 2 threads per (n,c) target.
    if (t < 90) {
        int j = t >> 1, half = t & 1;
        int f = r * 45 + j, n = f >> 1, c = f & 1;
        const float* base = ws_f + OFF_P2 + n * 2 + c;
        float s = 0.f;
        #pragma unroll 9
        for (int p = half * 45; p < half * 45 + 45; ++p)
            s += base[p * PBINS * 2];
        sred[j][half] = s;
    }
    __syncthreads();

    // Phase B: assemble the 113-wide concat row (bias + relu).
    if (t < 113) {
        float v;
        if (t < 68) {
            int f = r * 68 + t;                       // h1.reshape(250,68) flat
            v = ws_f[OFF_G1 + f] + b1[f % 200];
        } else {
            int j = t - 68;
            int f = r * 45 + j, n = f >> 1, c = f & 1;
            float sum = ws_f[OFF_HS2 + n * 2 + c]     // self loop: dinv*h2
                      + sred[j][0] + sred[j][1];
            v = ws_f[OFF_DINV + n] * sum + b2[c];
        }
        sh[t] = fmaxf(v, 0.f);
    }
    __syncthreads();

    // Phase C: final 113x5 linear; 5 outputs x 16-lane shuffle groups.
    if (t < 80) {
        int o = t >> 4, l = t & 15;
        float s = 0.f;
        for (int k = l; k < 113; k += 16)
            s = fmaf(sh[k], Wf[k * 5 + o], s);
        #pragma unroll
        for (int m = 8; m >= 1; m >>= 1) s += __shfl_down(s, m, 16);
        if (l == 0) out[r * 5 + o] = s + bf[o];
    }
}

extern "C" void kernel_launch(void* const* d_in, const int* in_sizes, int n_in,
                              void* d_out, int out_size, void* d_ws, size_t ws_size,
                              hipStream_t stream)
{
    const float* x1 = (const float*)d_in[0];
    const float* x2 = (const float*)d_in[1];
    const float* W1 = (const float*)d_in[2];
    const float* b1 = (const float*)d_in[3];
    const float* W2 = (const float*)d_in[4];
    const float* b2 = (const float*)d_in[5];
    const float* Wf = (const float*)d_in[6];
    const float* bf = (const float*)d_in[7];
    const int*   ei1 = (const int*)d_in[8];
    const int*   ei2 = (const int*)d_in[9];
    float* ws_f = (float*)d_ws;
    float* out  = (float*)d_out;

    kA_hist_gemm1<<<KA_GRID, 256, 0, stream>>>(x1, W1, ei1, ei2, ws_f);
    kB_gemm2_table<<<KB_GRID, 256, 0, stream>>>(x2, W2, ws_f);
    kC_gather<<<KC_GRID, 256, 0, stream>>>(ei1, ei2, ws_f);
    kD_head<<<250, 128, 0, stream>>>(ws_f, b1, b2, Wf, bf, out);
}